// Round 13
// baseline (157.373 us; speedup 1.0000x reference)
//
#include <hip/hip_runtime.h>

// MoE router, fp32-accurate via bf16-split MFMA (verified absmax 9.8e-4).
// x = token_inputs * jitter; logits = x @ w + b; softmax E=64; top-2 mask.
// Tokens = 32768, H = 2048, E = 64.
//
// R13: DRAM-page-locality attack. R9-R12: four structures, occupancy 22-50%,
// all ~3.5 TB/s effective -- because every fragment-layout load touched 16
// cache lines on 16 DIFFERENT 8-KB token rows (16 page streams/instr;
// ~65K chip-wide). R13 makes every x/j load 1 KB CONTIGUOUS within one row
// (one page burst, like the 6.3 TB/s copy kernel): wave stages [16 tok x
// 256 k] per chunk via 16 single-row instructions, converts to bf16 hi/lo,
// ds_writes into a wave-private swizzled plane, then runs 8 MFMA k-steps
// reading frags back. Single-buffered, DS in-order, ZERO barriers in loop.
// K-split 2; block = 4 waves / 32 tokens; 64 KB LDS -> 2 blocks/CU.

#define H   2048
#define E   64

typedef __attribute__((ext_vector_type(8))) short bf16x8;
typedef __attribute__((ext_vector_type(4))) float f32x4;

__device__ inline unsigned bfhi(float f) {            // f32 -> bf16 (RNE), as u32
    union { float f; unsigned u; } c; c.f = f;
    return (c.u + 0x7FFFu + ((c.u >> 16) & 1u)) >> 16;
}
__device__ inline float bf2f(unsigned h) {
    union { unsigned u; float f; } c; c.u = h << 16;
    return c.f;
}

// ---- pre-kernel: pack w into fragment-linear hi/lo bf16 (verified) ----
// frag-pair (ks,n): hi at bp+(ks*4+n)*1024 (+lane*8), lo at +512.
// slot s of lane (g,c) holds w[ks*32 + g*8 + s][n*16 + c].
__global__ __launch_bounds__(256)
void wpack_kernel(const float* __restrict__ w, ushort* __restrict__ bp)
{
    const int t    = blockIdx.x * 256 + threadIdx.x;  // 0..16383
    const int lane = t & 63;
    const int n    = (t >> 6) & 3;
    const int ks   = t >> 8;                          // 0..63
    const int c    = lane & 15, g = lane >> 4;

    const float* src = w + (size_t)(ks * 32 + g * 8) * E + n * 16 + c;
    bf16x8 vh, vl;
#pragma unroll
    for (int s = 0; s < 8; ++s) {
        const float v = src[(size_t)s * E];
        const unsigned h = bfhi(v);
        vh[s] = (short)h;
        vl[s] = (short)bfhi(v - bf2f(h));
    }
    ushort* d = bp + ((size_t)(ks * 4 + n) * 2 * 64 + lane) * 8;
    *(bf16x8*)d         = vh;
    *(bf16x8*)(d + 512) = vl;
}

// ---- main kernel ----
__global__ __launch_bounds__(256, 2)
void router_kernel(const float* __restrict__ xg,
                   const float* __restrict__ jg,
                   const ushort* __restrict__ bp,
                   const float* __restrict__ bias,
                   float* __restrict__ out)
{
    // per-wave 16 KB plane: hi [16 tok][256 k] ushort (8 KB) + lo (8 KB).
    // k-granule (16 B = 8 ushorts) kg of row i stored at granule kg ^ (i&7).
    // Epilogue overlays lgx[2][32][68] f32 on the arena (after a barrier).
    __shared__ __align__(16) unsigned char arena[65536];

    const int tid  = threadIdx.x;
    const int wv   = tid >> 6;
    const int lane = tid & 63;
    const int tc   = lane & 15;        // A-row token / D col expert
    const int g    = lane >> 4;        // k-group
    const int th   = wv & 1;           // token half (0:0-15, 1:16-31)
    const int kh   = wv >> 1;          // k half
    const size_t tokBase = (size_t)blockIdx.x * 32;
    const size_t rowBase = tokBase + th * 16;

    ushort* hiP = (ushort*)(arena + wv * 16384);
    ushort* loP = hiP + 4096;

    const ushort* bpw = bp + (size_t)lane * 8;

    f32x4 acc0 = (f32x4){0.f, 0.f, 0.f, 0.f};
    f32x4 acc1 = (f32x4){0.f, 0.f, 0.f, 0.f};
    f32x4 acc2 = (f32x4){0.f, 0.f, 0.f, 0.f};
    f32x4 acc3 = (f32x4){0.f, 0.f, 0.f, 0.f};

    // staging write address components (lane covers k = lane*4..lane*4+4)
    const int wgr  = lane >> 1;        // k-granule this lane writes
    const int whf  = (lane & 1) * 4;   // ushort offset within granule

#pragma unroll 1
    for (int cc = 0; cc < 4; ++cc) {
        const size_t kb = (size_t)kh * 1024 + (size_t)cc * 256 + lane * 4;

        // ---- stage: 16 page-sequential 1-KB row loads, 2 groups of 8 ----
#pragma unroll
        for (int grp = 0; grp < 2; ++grp) {
            float4 xr[8], jr[8];
#pragma unroll
            for (int i = 0; i < 8; ++i) {
                const size_t row = rowBase + grp * 8 + i;
                xr[i] = *(const float4*)(xg + row * H + kb);
                jr[i] = *(const float4*)(jg + row * H + kb);
            }
            __builtin_amdgcn_sched_barrier(0);   // pin: all 16 loads issued
#pragma unroll
            for (int i = 0; i < 8; ++i) {
                const int ri = grp * 8 + i;
                const float p0 = xr[i].x * jr[i].x;
                const float p1 = xr[i].y * jr[i].y;
                const float p2 = xr[i].z * jr[i].z;
                const float p3 = xr[i].w * jr[i].w;
                const unsigned h0 = bfhi(p0), h1 = bfhi(p1);
                const unsigned h2 = bfhi(p2), h3 = bfhi(p3);
                const unsigned l0 = bfhi(p0 - bf2f(h0));
                const unsigned l1 = bfhi(p1 - bf2f(h1));
                const unsigned l2 = bfhi(p2 - bf2f(h2));
                const unsigned l3 = bfhi(p3 - bf2f(h3));
                const int idx = ri * 256 + ((wgr ^ (ri & 7)) << 3) + whf;
                uint2 hv; hv.x = h0 | (h1 << 16); hv.y = h2 | (h3 << 16);
                uint2 lv; lv.x = l0 | (l1 << 16); lv.y = l2 | (l3 << 16);
                *(uint2*)&hiP[idx] = hv;
                *(uint2*)&loP[idx] = lv;
            }
        }

        // ---- compute: 8 MFMA k-steps (DS in-order: reads see the writes) ----
#pragma unroll
        for (int ks = 0; ks < 8; ++ks) {
            const int rg  = ((ks * 4 + g) ^ (tc & 7)) << 3;
            const bf16x8 ah = *(const bf16x8*)&hiP[tc * 256 + rg];
            const bf16x8 al = *(const bf16x8*)&loP[tc * 256 + rg];

            const int gks = kh * 32 + cc * 8 + ks;
            const ushort* bq = bpw + (size_t)gks * 4096;
            {
                const bf16x8 BH = *(const bf16x8*)(bq);
                const bf16x8 BL = *(const bf16x8*)(bq + 512);
                acc0 = __builtin_amdgcn_mfma_f32_16x16x32_bf16(ah, BH, acc0, 0, 0, 0);
                acc0 = __builtin_amdgcn_mfma_f32_16x16x32_bf16(al, BH, acc0, 0, 0, 0);
                acc0 = __builtin_amdgcn_mfma_f32_16x16x32_bf16(ah, BL, acc0, 0, 0, 0);
            }
            {
                const bf16x8 BH = *(const bf16x8*)(bq + 1024);
                const bf16x8 BL = *(const bf16x8*)(bq + 1536);
                acc1 = __builtin_amdgcn_mfma_f32_16x16x32_bf16(ah, BH, acc1, 0, 0, 0);
                acc1 = __builtin_amdgcn_mfma_f32_16x16x32_bf16(al, BH, acc1, 0, 0, 0);
                acc1 = __builtin_amdgcn_mfma_f32_16x16x32_bf16(ah, BL, acc1, 0, 0, 0);
            }
            {
                const bf16x8 BH = *(const bf16x8*)(bq + 2048);
                const bf16x8 BL = *(const bf16x8*)(bq + 2560);
                acc2 = __builtin_amdgcn_mfma_f32_16x16x32_bf16(ah, BH, acc2, 0, 0, 0);
                acc2 = __builtin_amdgcn_mfma_f32_16x16x32_bf16(al, BH, acc2, 0, 0, 0);
                acc2 = __builtin_amdgcn_mfma_f32_16x16x32_bf16(ah, BL, acc2, 0, 0, 0);
            }
            {
                const bf16x8 BH = *(const bf16x8*)(bq + 3072);
                const bf16x8 BL = *(const bf16x8*)(bq + 3584);
                acc3 = __builtin_amdgcn_mfma_f32_16x16x32_bf16(ah, BH, acc3, 0, 0, 0);
                acc3 = __builtin_amdgcn_mfma_f32_16x16x32_bf16(al, BH, acc3, 0, 0, 0);
                acc3 = __builtin_amdgcn_mfma_f32_16x16x32_bf16(ah, BL, acc3, 0, 0, 0);
            }
        }
    }

    // ---- all waves done with staging planes; overlay the logit exchange ----
    __syncthreads();
    float (*lgx)[32][68] = (float (*)[32][68])(void*)arena;   // [kh][tok][exp]
#pragma unroll
    for (int r = 0; r < 4; ++r) {
        const int trow = th * 16 + g * 4 + r;     // D map: row=(l>>4)*4+r
        lgx[kh][trow][     tc] = acc0[r];         //         col=l&15
        lgx[kh][trow][16 + tc] = acc1[r];
        lgx[kh][trow][32 + tc] = acc2[r];
        lgx[kh][trow][48 + tc] = acc3[r];
    }
    __syncthreads();

    // ---- epilogue: 8 threads/token x 32 tokens = 256 threads (verified) ----
    const int t8 = tid >> 3;           // token 0..31
    const int q8 = tid & 7;            // expert octet
    const int eb = q8 * 8;

    float l[8];
    {
        const float4 a0 = *(const float4*)&lgx[0][t8][eb];
        const float4 a1 = *(const float4*)&lgx[1][t8][eb];
        const float4 b0 = *(const float4*)&lgx[0][t8][eb + 4];
        const float4 b1 = *(const float4*)&lgx[1][t8][eb + 4];
        const float4 bb0 = *(const float4*)(bias + eb);
        const float4 bb1 = *(const float4*)(bias + eb + 4);
        l[0] = a0.x + a1.x + bb0.x;  l[1] = a0.y + a1.y + bb0.y;
        l[2] = a0.z + a1.z + bb0.z;  l[3] = a0.w + a1.w + bb0.w;
        l[4] = b0.x + b1.x + bb1.x;  l[5] = b0.y + b1.y + bb1.y;
        l[6] = b0.z + b1.z + bb1.z;  l[7] = b0.w + b1.w + bb1.w;
    }

    // local top-2 (strict '>' ascending keeps lowest index on ties)
    float p1 = l[0]; int i1 = eb;
    float p2 = -3.0e38f; int i2 = eb;
#pragma unroll
    for (int i = 1; i < 8; ++i) {
        const int e = eb + i;
        if (l[i] > p1)      { p2 = p1; i2 = i1; p1 = l[i]; i1 = e; }
        else if (l[i] > p2) { p2 = l[i]; i2 = e; }
    }

    // butterfly merge across the token's 8 threads
#pragma unroll
    for (int m = 1; m <= 4; m <<= 1) {
        const float q1 = __shfl_xor(p1, m, 8);
        const int   k1 = __shfl_xor(i1, m, 8);
        const float q2 = __shfl_xor(p2, m, 8);
        const int   k2 = __shfl_xor(i2, m, 8);
        const bool  bw = (q1 > p1) || (q1 == p1 && k1 < i1);
        const float f1 = bw ? q1 : p1;  const int fi1 = bw ? k1 : i1;
        const float lo = bw ? p1 : q1;  const int loi = bw ? i1 : k1;
        const float sn = bw ? q2 : p2;  const int sni = bw ? k2 : i2;
        const bool  rw = (lo > sn) || (lo == sn && loi < sni);
        p2 = rw ? lo : sn;  i2 = rw ? loi : sni;
        p1 = f1;            i1 = fi1;
    }

    float d = 0.f;
#pragma unroll
    for (int i = 0; i < 8; ++i) d += __expf(l[i] - p1);
#pragma unroll
    for (int m = 1; m <= 4; m <<= 1) d += __shfl_xor(d, m, 8);

    const float inv = 1.f / d;                 // top-1 prob
    const float w2  = __expf(p2 - p1) * inv;   // top-2 prob

    float* op = out + (tokBase + t8) * (size_t)E + eb;
    float4 v0, v1;
    v0.x = (eb + 0 == i1) ? inv : (eb + 0 == i2) ? w2 : 0.f;
    v0.y = (eb + 1 == i1) ? inv : (eb + 1 == i2) ? w2 : 0.f;
    v0.z = (eb + 2 == i1) ? inv : (eb + 2 == i2) ? w2 : 0.f;
    v0.w = (eb + 3 == i1) ? inv : (eb + 3 == i2) ? w2 : 0.f;
    v1.x = (eb + 4 == i1) ? inv : (eb + 4 == i2) ? w2 : 0.f;
    v1.y = (eb + 5 == i1) ? inv : (eb + 5 == i2) ? w2 : 0.f;
    v1.z = (eb + 6 == i1) ? inv : (eb + 6 == i2) ? w2 : 0.f;
    v1.w = (eb + 7 == i1) ? inv : (eb + 7 == i2) ? w2 : 0.f;
    *(float4*)op       = v0;
    *(float4*)(op + 4) = v1;
}

extern "C" void kernel_launch(void* const* d_in, const int* in_sizes, int n_in,
                              void* d_out, int out_size, void* d_ws, size_t ws_size,
                              hipStream_t stream)
{
    const float* x   = (const float*)d_in[0];
    const float* jit = (const float*)d_in[1];
    const float* w   = (const float*)d_in[2];
    const float* b   = (const float*)d_in[3];
    float*       out = (float*)d_out;

    ushort* bpack = (ushort*)d_ws;   // 512 frag-pairs x 1 KB = 512 KB

    hipLaunchKernelGGL(wpack_kernel, dim3(64), dim3(256), 0, stream, w, bpack);

    const int n_tok = in_sizes[0] / H;   // 32768
    dim3 grid(n_tok / 32), block(256);
    hipLaunchKernelGGL(router_kernel, grid, block, 0, stream,
                       x, jit, bpack, b, out);
}

// Round 14
// 122.998 us; speedup vs baseline: 1.2795x; 1.2795x over previous
//
#include <hip/hip_runtime.h>

// MoE router, fp32-accurate via bf16-split MFMA (verified absmax 9.8e-4).
// x = token_inputs * jitter; logits = x @ w + b; softmax E=64; top-2 mask.
// Tokens = 32768, H = 2048, E = 64.
//
// R14 = R6 verbatim (best timed: 122 us). Rationale: rounds 7-13 tested and
// FALSIFIED five bottleneck hypotheses (vmcnt ordering, barrier drain,
// LDS-DMA alias tracking, occupancy/TLP, DRAM page locality) -- all eight
// structures cluster at 122-161 us timed with every pipe <=20% utilized.
// Effective input consumption at R6 is ~4.3 TB/s, plausibly the read-path
// knee for a dual 256-MB stream + L2 B-traffic mix (the 6.3 TB/s ubench is
// a COPY: read+write summed). Reverting to the best-known kernel both locks
// in the optimum and measures single-kernel reproducibility (122 was a
// single observation; the structure family spans 122-148).
//
// Structure: wave = 16 tokens x 64 experts, full K, block = 4 waves.
// A-side: x,j loaded coalesced, product staged f32 in wave-private LDS
// (2KB/chunk, dbuf, XOR swizzle), frags via ds_read_b128; no barriers.
// B-side: fragment-linear hi/lo bf16 pack in d_ws (L2-resident).
// Epilogue: in-register softmax + top-2 within 16-lane groups.

#define H   2048
#define E   64
#define NKS 64          // k-steps of 32

typedef __attribute__((ext_vector_type(8))) short bf16x8;
typedef __attribute__((ext_vector_type(4))) float f32x4;

__device__ inline ushort f2bf_rne(float f) {
    union { float f; unsigned u; } c; c.f = f;
    const unsigned r = (c.u + 0x7FFFu + ((c.u >> 16) & 1u)) >> 16;
    return (ushort)r;
}
__device__ inline float bf2f(ushort h) {
    union { unsigned u; float f; } c; c.u = ((unsigned)h) << 16;
    return c.f;
}

// ---- pre-kernel: pack w into fragment-linear hi/lo bf16 ----
// frag fi = (ks*4 + n)*2 + p ; element: lane(g,c), slot s ->
//   w[ks*32 + g*8 + s][n*16 + c]   (A and B share the same slot->k map,
//   so contiguous-8 packing is correct independent of HW's internal order)
__global__ __launch_bounds__(256)
void wpack_kernel(const float* __restrict__ w, ushort* __restrict__ bp)
{
    const int t    = blockIdx.x * 256 + threadIdx.x;  // 0..16383
    const int lane = t & 63;
    const int n    = (t >> 6) & 3;
    const int ks   = t >> 8;                          // 0..63
    const int c    = lane & 15, g = lane >> 4;

    const float* src = w + (size_t)(ks * 32 + g * 8) * E + n * 16 + c;
    bf16x8 vh, vl;
#pragma unroll
    for (int s = 0; s < 8; ++s) {
        const float  v = src[(size_t)s * E];
        const ushort h = f2bf_rne(v);
        vh[s] = (short)h;
        vl[s] = (short)f2bf_rne(v - bf2f(h));
    }
    ushort* d = bp + ((size_t)(ks * 4 + n) * 2 * 64 + lane) * 8;
    *(bf16x8*)d         = vh;     // p=0 (hi)
    *(bf16x8*)(d + 512) = vl;     // p=1 (lo), next frag
}

// ---- main kernel ----
__global__ __launch_bounds__(256, 2)
void router_kernel(const float* __restrict__ xg,
                   const float* __restrict__ jg,
                   const ushort* __restrict__ bp,
                   const float* __restrict__ bias,
                   float* __restrict__ out)
{
    // wave-private staging of x*j: element (tok, f4) at prod[wv][buf][tok][f4 ^ (tok&7)]
    __shared__ __align__(16) float prod[4][2][16][8][4];   // 16 KB

    const int tid  = threadIdx.x;
    const int wv   = tid >> 6;
    const int lane = tid & 63;
    const int ln   = lane & 15;          // token-in-tile / expert col
    const int g    = lane >> 4;          // k-group
    const size_t tokBase = (size_t)blockIdx.x * 64 + (size_t)wv * 16;

    // staging coords: lane covers (tok = stok, stok+8), f4 = sf, per chunk
    const int stok = lane >> 3;          // 0..7
    const int sf   = lane & 7;           // 0..7
    const int swf  = sf ^ (stok & 7);    // same for stok and stok+8
    const float* xb = xg + (tokBase + stok) * H + sf * 4;
    const float* jb = jg + (tokBase + stok) * H + sf * 4;

    f32x4 acc[4];
#pragma unroll
    for (int n = 0; n < 4; ++n) acc[n] = (f32x4){0.f, 0.f, 0.f, 0.f};

    float4 xe0, xe1, je0, je1;   // even-chunk regs
    float4 xo0, xo1, jo0, jo1;   // odd-chunk regs
    bf16x8 BH0[4], BL0[4], BH1[4], BL1[4];

#define LOAD_XJ(X0, J0, X1, J1, c) do {                         \
        const size_t o_ = (size_t)(c) * 32;                     \
        X0 = *(const float4*)(xb + o_);                         \
        J0 = *(const float4*)(jb + o_);                         \
        X1 = *(const float4*)(xb + o_ + 8 * (size_t)H);         \
        J1 = *(const float4*)(jb + o_ + 8 * (size_t)H);         \
    } while (0)

#define WRITE_STAGE(b, X0, J0, X1, J1) do {                     \
        float4 q0, q1;                                          \
        q0.x = X0.x * J0.x; q0.y = X0.y * J0.y;                 \
        q0.z = X0.z * J0.z; q0.w = X0.w * J0.w;                 \
        q1.x = X1.x * J1.x; q1.y = X1.y * J1.y;                 \
        q1.z = X1.z * J1.z; q1.w = X1.w * J1.w;                 \
        *(float4*)&prod[wv][b][stok][swf][0]     = q0;          \
        *(float4*)&prod[wv][b][stok + 8][swf][0] = q1;          \
    } while (0)

#define LOAD_B(BH, BL, ks) do {                                             \
        _Pragma("unroll")                                                   \
        for (int n_ = 0; n_ < 4; ++n_) {                                    \
            const ushort* p_ = bp + (size_t)((ks) * 4 + n_) * 1024 + lane * 8; \
            BH[n_] = *(const bf16x8*)p_;                                    \
            BL[n_] = *(const bf16x8*)(p_ + 512);                            \
        }                                                                   \
    } while (0)

#define KSTEP(rb, BH, BL) do {                                              \
        const int f0s_ = (g * 2) ^ (ln & 7);                                \
        float p_[8];                                                        \
        *(float4*)&p_[0] = *(const float4*)&prod[wv][rb][ln][f0s_][0];      \
        *(float4*)&p_[4] = *(const float4*)&prod[wv][rb][ln][f0s_ ^ 1][0];  \
        bf16x8 ah_, al_;                                                    \
        _Pragma("unroll")                                                   \
        for (int i_ = 0; i_ < 8; ++i_) {                                    \
            const ushort h_ = f2bf_rne(p_[i_]);                             \
            ah_[i_] = (short)h_;                                            \
            al_[i_] = (short)f2bf_rne(p_[i_] - bf2f(h_));                   \
        }                                                                   \
        _Pragma("unroll")                                                   \
        for (int n_ = 0; n_ < 4; ++n_) {                                    \
            acc[n_] = __builtin_amdgcn_mfma_f32_16x16x32_bf16(ah_, BH[n_], acc[n_], 0, 0, 0); \
            acc[n_] = __builtin_amdgcn_mfma_f32_16x16x32_bf16(al_, BH[n_], acc[n_], 0, 0, 0); \
            acc[n_] = __builtin_amdgcn_mfma_f32_16x16x32_bf16(ah_, BL[n_], acc[n_], 0, 0, 0); \
        }                                                                   \
    } while (0)

    // ---- prologue ----
    LOAD_XJ(xe0, je0, xe1, je1, 0);
    LOAD_XJ(xo0, jo0, xo1, jo1, 1);
    LOAD_B(BH0, BL0, 0);
    WRITE_STAGE(0, xe0, je0, xe1, je1);      // chunk 0 -> buf 0

    // ---- main loop, unrolled x2 (even/odd named sets) ----
    for (int c = 0; c < NKS; c += 2) {
        // even half: compute chunk c
        {
            const int cl = (c + 2 < NKS) ? c + 2 : NKS - 1;
            LOAD_XJ(xe0, je0, xe1, je1, cl);            // chunk c+2 in flight
            const int kl = (c + 1 < NKS) ? c + 1 : NKS - 1;
            LOAD_B(BH1, BL1, kl);                       // B for c+1
            KSTEP(0, BH0, BL0);
            WRITE_STAGE(1, xo0, jo0, xo1, jo1);         // stage chunk c+1
        }
        // odd half: compute chunk c+1
        {
            const int cl = (c + 3 < NKS) ? c + 3 : NKS - 1;
            LOAD_XJ(xo0, jo0, xo1, jo1, cl);            // chunk c+3 in flight
            const int kl = (c + 2 < NKS) ? c + 2 : NKS - 1;
            LOAD_B(BH0, BL0, kl);                       // B for c+2
            KSTEP(1, BH1, BL1);
            WRITE_STAGE(0, xe0, je0, xe1, je1);         // stage chunk c+2
        }
    }

    // ---- epilogue: softmax + top-2 per token within 16-lane groups (verified) ----
    const float b0 = bias[ln], b1 = bias[16 + ln], b2 = bias[32 + ln], b3 = bias[48 + ln];
    float* outw = out + tokBase * E;

#pragma unroll
    for (int r = 0; r < 4; ++r) {
        const float v0 = acc[0][r] + b0;
        const float v1 = acc[1][r] + b1;
        const float v2 = acc[2][r] + b2;
        const float v3 = acc[3][r] + b3;

        float p1 = v0; int i1 = ln;
        float p2 = -3.0e38f; int i2 = ln;
        if (v1 > p1)      { p2 = p1; i2 = i1; p1 = v1; i1 = 16 + ln; }
        else if (v1 > p2) { p2 = v1; i2 = 16 + ln; }
        if (v2 > p1)      { p2 = p1; i2 = i1; p1 = v2; i1 = 32 + ln; }
        else if (v2 > p2) { p2 = v2; i2 = 32 + ln; }
        if (v3 > p1)      { p2 = p1; i2 = i1; p1 = v3; i1 = 48 + ln; }
        else if (v3 > p2) { p2 = v3; i2 = 48 + ln; }

#pragma unroll
        for (int m = 1; m <= 8; m <<= 1) {
            const float q1 = __shfl_xor(p1, m, 16);
            const int   k1 = __shfl_xor(i1, m, 16);
            const float q2 = __shfl_xor(p2, m, 16);
            const int   k2 = __shfl_xor(i2, m, 16);
            const bool  bw = (q1 > p1) || (q1 == p1 && k1 < i1);
            const float f1 = bw ? q1 : p1;  const int fi1 = bw ? k1 : i1;
            const float lo = bw ? p1 : q1;  const int loi = bw ? i1 : k1;
            const float sn = bw ? q2 : p2;  const int sni = bw ? k2 : i2;
            const bool  rw = (lo > sn) || (lo == sn && loi < sni);
            p2 = rw ? lo : sn;  i2 = rw ? loi : sni;
            p1 = f1;            i1 = fi1;
        }

        float d = __expf(v0 - p1) + __expf(v1 - p1) + __expf(v2 - p1) + __expf(v3 - p1);
#pragma unroll
        for (int m = 1; m <= 8; m <<= 1) d += __shfl_xor(d, m, 16);

        const float inv = 1.f / d;
        const float w2  = __expf(p2 - p1) * inv;

        const size_t trow = (size_t)(g * 4 + r) * E;
        outw[trow +      ln] = (     ln == i1) ? inv : (     ln == i2) ? w2 : 0.f;
        outw[trow + 16 + ln] = (16 + ln == i1) ? inv : (16 + ln == i2) ? w2 : 0.f;
        outw[trow + 32 + ln] = (32 + ln == i1) ? inv : (32 + ln == i2) ? w2 : 0.f;
        outw[trow + 48 + ln] = (48 + ln == i1) ? inv : (48 + ln == i2) ? w2 : 0.f;
    }
}

extern "C" void kernel_launch(void* const* d_in, const int* in_sizes, int n_in,
                              void* d_out, int out_size, void* d_ws, size_t ws_size,
                              hipStream_t stream)
{
    const float* x   = (const float*)d_in[0];
    const float* jit = (const float*)d_in[1];
    const float* w   = (const float*)d_in[2];
    const float* b   = (const float*)d_in[3];
    float*       out = (float*)d_out;

    ushort* bpack = (ushort*)d_ws;   // 512 frags x 1 KB = 512 KB

    hipLaunchKernelGGL(wpack_kernel, dim3(64), dim3(256), 0, stream, w, bpack);

    const int n_tok = in_sizes[0] / H;   // 32768
    dim3 grid(n_tok / 64), block(256);
    hipLaunchKernelGGL(router_kernel, grid, block, 0, stream,
                       x, jit, bpack, b, out);
}